// Round 6
// baseline (244.063 us; speedup 1.0000x reference)
//
#include <hip/hip_runtime.h>
#include <hip/hip_bf16.h>

typedef short s16x8 __attribute__((ext_vector_type(8)));
typedef float f32x4 __attribute__((ext_vector_type(4)));

#define LOG2E_2 2.8853900817779268f  // 2*log2(e)

__device__ __forceinline__ float fexp2(float x){ return __builtin_amdgcn_exp2f(x); }
__device__ __forceinline__ float frcp (float x){ return __builtin_amdgcn_rcpf(x); }
__device__ __forceinline__ float ftanh(float v){
    return 1.0f - 2.0f * frcp(1.0f + fexp2(LOG2E_2 * v));
}
__device__ __forceinline__ unsigned short f2bf(float v){
    __hip_bfloat16 h = __float2bfloat16(v);
    return __builtin_bit_cast(unsigned short, h);
}
__device__ __forceinline__ float bf2f(unsigned short u){
    return __bfloat162float(__builtin_bit_cast(__hip_bfloat16, u));
}
__device__ __forceinline__ f32x4 mfma32(s16x8 a, s16x8 b, f32x4 c){
    return __builtin_amdgcn_mfma_f32_16x16x32_bf16(a, b, c, 0, 0, 0);
}
// split fp32x4 -> bf16 hi + residual lo (identical rounding path since round 0)
__device__ __forceinline__ void cvt4(float4 v, ushort4& h, ushort4& l){
    h.x = f2bf(v.x); l.x = f2bf(v.x - bf2f(h.x));
    h.y = f2bf(v.y); l.y = f2bf(v.y - bf2f(h.y));
    h.z = f2bf(v.z); l.z = f2bf(v.z - bf2f(h.z));
    h.w = f2bf(v.w); l.w = f2bf(v.w - bf2f(h.w));
}

// ---------- K1 v3: hv = tanh(x @ [Wfoh|Wfom] + cb) -- fp32 in, split inline ----------
// (unchanged from round 5) 32m x 32n tiles, grid (32,32)=1024 blocks, dbuf LDS.
__global__ __launch_bounds__(256) void k1_fused(
    const float* __restrict__ l0, const float* __restrict__ l1,
    const float* __restrict__ Wfoh, const float* __restrict__ Wfom,
    const float* __restrict__ cb,
    unsigned short* __restrict__ hvhi, unsigned short* __restrict__ hvlo)
{
    __shared__ unsigned short Ah[2][32][40], Al[2][32][40], Bh[2][32][40], Bl[2][32][40];
    const int t = threadIdx.x;
    const int r0 = blockIdx.y * 32, c0 = blockIdx.x * 32;
    const int w = t >> 6, lane = t & 63;
    const int m = lane & 15, quad = lane >> 4;
    const int wm = w & 1, wn = w >> 1;

    const int arow = t >> 3, aseg = t & 7;   // A: float4 @ k-cols aseg*4, row arow
    const int nn = t & 31, kq = t >> 5;      // B: col nn, k rows kq*4..kq*4+3

    const float* xr0 = l0 + (r0+arow)*256 + aseg*4;
    const float* xr1 = l1 + (r0+arow)*256 + aseg*4;
    const float* wcol = (c0 < 512) ? (Wfoh + c0 + nn) : (Wfom + (c0 - 512) + nn);

    f32x4 acc = {0,0,0,0};

    float4 fa, fb;
    #define K1_LOAD(k0_) do { \
        const float* pa_ = ((k0_) < 256) ? (xr0 + (k0_)) : (xr1 + ((k0_) - 256)); \
        fa = *(const float4*)pa_; \
        const float* pb_ = wcol + ((k0_) + kq*4) * 512; \
        fb.x = pb_[0]; fb.y = pb_[512]; fb.z = pb_[1024]; fb.w = pb_[1536]; \
    } while(0)
    #define K1_STAGE(buf_) do { \
        ushort4 ah_, al_, bh_, bl_; \
        cvt4(fa, ah_, al_); cvt4(fb, bh_, bl_); \
        *(ushort4*)&Ah[buf_][arow][aseg*4] = ah_; \
        *(ushort4*)&Al[buf_][arow][aseg*4] = al_; \
        *(ushort4*)&Bh[buf_][nn][kq*4] = bh_; \
        *(ushort4*)&Bl[buf_][nn][kq*4] = bl_; \
    } while(0)

    K1_LOAD(0);
    K1_STAGE(0);
    K1_LOAD(32);
    __syncthreads();

    for (int c = 0; c < 16; ++c) {
        const int buf = c & 1;
        {
            const int ko = quad*8;
            s16x8 ah = *(const s16x8*)&Ah[buf][wm*16 + m][ko];
            s16x8 al = *(const s16x8*)&Al[buf][wm*16 + m][ko];
            s16x8 bh = *(const s16x8*)&Bh[buf][wn*16 + m][ko];
            s16x8 bl = *(const s16x8*)&Bl[buf][wn*16 + m][ko];
            acc = mfma32(ah, bh, acc);
            acc = mfma32(ah, bl, acc);
            acc = mfma32(al, bh, acc);
        }
        if (c + 1 < 16) {
            K1_STAGE(buf ^ 1);
            if (c + 2 < 16) K1_LOAD((c + 2) * 32);
            __syncthreads();
        }
    }
    #undef K1_LOAD
    #undef K1_STAGE

    {
        const int col = c0 + wn*16 + m;
        const float bias = cb[col];
        #pragma unroll
        for (int reg = 0; reg < 4; ++reg) {
            const int row = r0 + wm*16 + quad*4 + reg;
            float v = ftanh(acc[reg] + bias);
            unsigned short h = f2bf(v);
            unsigned short l = f2bf(v - bf2f(h));
            hvhi[row*1024 + col] = h;
            hvlo[row*1024 + col] = l;
        }
    }
}

// ---------- K2': P[1024][512] = exp2(LOG2E_2*(hv_half @ W2_half + bias)) ----------
// (unchanged from round 4/5) 32m x 32n, grid (16,32)=512 blocks, dbuf LDS.
__global__ __launch_bounds__(256) void k2_fused(
    const unsigned short* __restrict__ hvhi, const unsigned short* __restrict__ hvlo,
    const float* __restrict__ W2, const float* __restrict__ h2b,
    float* __restrict__ P)
{
    __shared__ unsigned short Ah[2][32][40], Al[2][32][40], Bh[2][32][40], Bl[2][32][40];
    const int t = threadIdx.x;
    const int r0 = blockIdx.y * 32, c0 = blockIdx.x * 32;
    const int half = (c0 >= 256) ? 1 : 0;
    const int ho = half * 512;
    const int nw = c0 & 255;
    const int w = t >> 6, lane = t & 63;
    const int m = lane & 15, quad = lane >> 4;
    const int wm = w & 1, wn = w >> 1;

    const int arow = t >> 3, aseg = t & 7;
    const int nn = t & 31, kq = t >> 5;

    const unsigned short* pAh = hvhi + (r0+arow)*1024 + ho + aseg*4;
    const unsigned short* pAl = hvlo + (r0+arow)*1024 + ho + aseg*4;
    const float* wcol = W2 + ho*256 + nw + nn;   // element k: wcol[k*256]

    f32x4 acc = {0,0,0,0};

    uint2 pa_h, pa_l;
    float4 fb;
    #define K2_LOAD(k0_) do { \
        pa_h = *(const uint2*)(pAh + (k0_)); \
        pa_l = *(const uint2*)(pAl + (k0_)); \
        const float* pb_ = wcol + ((k0_) + kq*4) * 256; \
        fb.x = pb_[0]; fb.y = pb_[256]; fb.z = pb_[512]; fb.w = pb_[768]; \
    } while(0)
    #define K2_STAGE(buf_) do { \
        ushort4 bh_, bl_; \
        cvt4(fb, bh_, bl_); \
        *(uint2*)&Ah[buf_][arow][aseg*4] = pa_h; \
        *(uint2*)&Al[buf_][arow][aseg*4] = pa_l; \
        *(ushort4*)&Bh[buf_][nn][kq*4] = bh_; \
        *(ushort4*)&Bl[buf_][nn][kq*4] = bl_; \
    } while(0)

    K2_LOAD(0);
    K2_STAGE(0);
    K2_LOAD(32);
    __syncthreads();

    for (int c = 0; c < 16; ++c) {
        const int buf = c & 1;
        {
            const int ko = quad*8;
            s16x8 ah = *(const s16x8*)&Ah[buf][wm*16 + m][ko];
            s16x8 al = *(const s16x8*)&Al[buf][wm*16 + m][ko];
            s16x8 bh = *(const s16x8*)&Bh[buf][wn*16 + m][ko];
            s16x8 bl = *(const s16x8*)&Bl[buf][wn*16 + m][ko];
            acc = mfma32(ah, bh, acc);
            acc = mfma32(ah, bl, acc);
            acc = mfma32(al, bh, acc);
        }
        if (c + 1 < 16) {
            K2_STAGE(buf ^ 1);
            if (c + 2 < 16) K2_LOAD((c + 2) * 32);
            __syncthreads();
        }
    }
    #undef K2_LOAD
    #undef K2_STAGE

    {
        const int col = c0 + wn*16 + m;
        const float bias = half ? 0.0f : h2b[col];
        #pragma unroll
        for (int reg = 0; reg < 4; ++reg) {
            const int row = r0 + wm*16 + quad*4 + reg;
            P[row*512 + col] = fexp2((acc[reg] + bias) * LOG2E_2);
        }
    }
}

// ---------- K3 v6: score[i,j] = ob + sumw - 2*sum_h w[h]/(1 + ea[i,h]*eb[j,h]) ----------
// Revert to v4 structure (32x32 tile, 2x2 outputs/thread, grid (32,32)=1024 blocks
// -> 4 blocks/CU, A=4 amortization) + FULL unroll of the hh loop so every ds_read
// has a compile-time-constant offset from a per-chunk base (kills the 33.6/A
// per-iteration overhead identified in R5 post-mortem). 4-way rcp combine kept.
__global__ __launch_bounds__(256) void k3_pairwise(
    const float* __restrict__ P, const float* __restrict__ w,
    const float* __restrict__ ob, float* __restrict__ out)
{
    __shared__ float As[2][32][68];   // ea chunk: [i][hh], 272B rows (16B aligned)
    __shared__ float Bs[2][32][68];   // eb chunk: [j][hh]
    __shared__ float wls[256];
    const int tid = threadIdx.x;
    const int tx = tid & 15;          // cols tx, tx+16
    const int ty = tid >> 4;          // rows ty, ty+16
    const int i0 = blockIdx.y * 32, j0 = blockIdx.x * 32;

    wls[tid] = w[tid];

    // staging: 32 rows x 64 h per chunk = 2048 floats; 8 floats (2 float4)/thread
    const int ar = tid >> 3, ac = (tid & 7) * 8;

    const float* pA = P + (i0 + ar) * 512 + ac;
    const float* pB = P + (j0 + ar) * 512 + 256 + ac;

    float4 ra0 = *(const float4*)(pA);
    float4 ra1 = *(const float4*)(pA + 4);
    float4 rb0 = *(const float4*)(pB);
    float4 rb1 = *(const float4*)(pB + 4);

    *(float4*)&As[0][ar][ac]   = ra0;
    *(float4*)&As[0][ar][ac+4] = ra1;
    *(float4*)&Bs[0][ar][ac]   = rb0;
    *(float4*)&Bs[0][ar][ac+4] = rb1;
    ra0 = *(const float4*)(pA + 64);
    ra1 = *(const float4*)(pA + 68);
    rb0 = *(const float4*)(pB + 64);
    rb1 = *(const float4*)(pB + 68);
    __syncthreads();

    float acc[2][2] = {};

    #pragma unroll 2
    for (int c = 0; c < 4; ++c) {
        const int buf = c & 1;
        // per-chunk bases: constant offsets below -> ds_read base+imm, no per-iter VALU
        const float* __restrict__ a0p = &As[buf][ty][0];
        const float* __restrict__ a1p = &As[buf][ty+16][0];
        const float* __restrict__ b0p = &Bs[buf][tx][0];
        const float* __restrict__ b1p = &Bs[buf][tx+16][0];
        const float* __restrict__ wp  = &wls[c*64];
        #pragma unroll
        for (int hh = 0; hh < 64; hh += 4) {
            float4 wv = *(const float4*)(wp + hh);
            float4 av[2], bv[2];
            av[0] = *(const float4*)(a0p + hh);
            av[1] = *(const float4*)(a1p + hh);
            bv[0] = *(const float4*)(b0p + hh);
            bv[1] = *(const float4*)(b1p + hh);
            #pragma unroll
            for (int r = 0; r < 2; ++r)
                #pragma unroll
                for (int q = 0; q < 2; ++q) {
                    float u0 = fmaf(av[r].x, bv[q].x, 1.0f);
                    float u1 = fmaf(av[r].y, bv[q].y, 1.0f);
                    float u2 = fmaf(av[r].z, bv[q].z, 1.0f);
                    float u3 = fmaf(av[r].w, bv[q].w, 1.0f);
                    float d01 = u0 * u1;
                    float d23 = u2 * u3;
                    float p01 = fmaf(wv.x, u1, wv.y * u0);
                    float p23 = fmaf(wv.z, u3, wv.w * u2);
                    float num = fmaf(p01, d23, p23 * d01);
                    acc[r][q] = fmaf(num, frcp(d01 * d23), acc[r][q]);
                }
        }
        if (c + 1 < 4) {
            const int nb = buf ^ 1;
            *(float4*)&As[nb][ar][ac]   = ra0;
            *(float4*)&As[nb][ar][ac+4] = ra1;
            *(float4*)&Bs[nb][ar][ac]   = rb0;
            *(float4*)&Bs[nb][ar][ac+4] = rb1;
            if (c + 2 < 4) {
                const int off = (c + 2) * 64;
                ra0 = *(const float4*)(pA + off);
                ra1 = *(const float4*)(pA + off + 4);
                rb0 = *(const float4*)(pB + off);
                rb1 = *(const float4*)(pB + off + 4);
            }
            __syncthreads();
        }
    }

    float sumw = 0.0f;
    #pragma unroll
    for (int h = 0; h < 256; h += 4) {
        float4 wv = *(const float4*)&wls[h];
        sumw += (wv.x + wv.y) + (wv.z + wv.w);
    }
    const float base = ob[0] + sumw;
    out[(i0+ty)*1024    + j0+tx]      = base - 2.0f * acc[0][0];
    out[(i0+ty)*1024    + j0+tx+16]   = base - 2.0f * acc[0][1];
    out[(i0+ty+16)*1024 + j0+tx]      = base - 2.0f * acc[1][0];
    out[(i0+ty+16)*1024 + j0+tx+16]   = base - 2.0f * acc[1][1];
}

extern "C" void kernel_launch(void* const* d_in, const int* in_sizes, int n_in,
                              void* d_out, int out_size, void* d_ws, size_t ws_size,
                              hipStream_t stream) {
    const float* l0   = (const float*)d_in[0];  // lstms0 [1024,256]
    const float* l1   = (const float*)d_in[1];  // lstms1 [1024,256]
    const float* Wfoh = (const float*)d_in[2];  // [512,512]
    const float* Wfom = (const float*)d_in[3];  // [512,512]
    const float* cb   = (const float*)d_in[4];  // [1024]
    const float* W2   = (const float*)d_in[5];  // [1024,256]
    const float* h2b  = (const float*)d_in[6];  // [256]
    const float* w    = (const float*)d_in[7];  // [256]
    const float* ob   = (const float*)d_in[8];  // [1]
    float* out = (float*)d_out;                 // [1024,1024]

    // ws layout: hv hi/lo (4MB) + P (2MB)
    unsigned short* hv_hi = (unsigned short*)d_ws;           // [1024][1024] bf16
    unsigned short* hv_lo = hv_hi + 1024*1024;
    float*          P     = (float*)(hv_lo + 1024*1024);     // [1024][512] fp32

    k1_fused<<<dim3(32,32), 256, 0, stream>>>(l0, l1, Wfoh, Wfom, cb, hv_hi, hv_lo);
    k2_fused<<<dim3(16,32), 256, 0, stream>>>(hv_hi, hv_lo, W2, h2b, P);
    k3_pairwise<<<dim3(32,32), 256, 0, stream>>>(P, w, ob, out);
}

// Round 7
// 120.577 us; speedup vs baseline: 2.0241x; 2.0241x over previous
//
#include <hip/hip_runtime.h>
#include <hip/hip_bf16.h>

typedef short s16x8 __attribute__((ext_vector_type(8)));
typedef float f32x4 __attribute__((ext_vector_type(4)));

#define LOG2E_2 2.8853900817779268f  // 2*log2(e)

__device__ __forceinline__ float fexp2(float x){ return __builtin_amdgcn_exp2f(x); }
__device__ __forceinline__ float frcp (float x){ return __builtin_amdgcn_rcpf(x); }
__device__ __forceinline__ float ftanh(float v){
    return 1.0f - 2.0f * frcp(1.0f + fexp2(LOG2E_2 * v));
}
__device__ __forceinline__ unsigned short f2bf(float v){
    __hip_bfloat16 h = __float2bfloat16(v);
    return __builtin_bit_cast(unsigned short, h);
}
__device__ __forceinline__ float bf2f(unsigned short u){
    return __bfloat162float(__builtin_bit_cast(__hip_bfloat16, u));
}
__device__ __forceinline__ f32x4 mfma32(s16x8 a, s16x8 b, f32x4 c){
    return __builtin_amdgcn_mfma_f32_16x16x32_bf16(a, b, c, 0, 0, 0);
}
// split fp32x4 -> bf16 hi + residual lo (identical rounding path since round 0)
__device__ __forceinline__ void cvt4(float4 v, ushort4& h, ushort4& l){
    h.x = f2bf(v.x); l.x = f2bf(v.x - bf2f(h.x));
    h.y = f2bf(v.y); l.y = f2bf(v.y - bf2f(h.y));
    h.z = f2bf(v.z); l.z = f2bf(v.z - bf2f(h.z));
    h.w = f2bf(v.w); l.w = f2bf(v.w - bf2f(h.w));
}

// ---------- K1 v3: hv = tanh(x @ [Wfoh|Wfom] + cb) -- fp32 in, split inline ----------
// (unchanged) 32m x 32n tiles, grid (32,32)=1024 blocks, dbuf LDS.
__global__ __launch_bounds__(256) void k1_fused(
    const float* __restrict__ l0, const float* __restrict__ l1,
    const float* __restrict__ Wfoh, const float* __restrict__ Wfom,
    const float* __restrict__ cb,
    unsigned short* __restrict__ hvhi, unsigned short* __restrict__ hvlo)
{
    __shared__ unsigned short Ah[2][32][40], Al[2][32][40], Bh[2][32][40], Bl[2][32][40];
    const int t = threadIdx.x;
    const int r0 = blockIdx.y * 32, c0 = blockIdx.x * 32;
    const int w = t >> 6, lane = t & 63;
    const int m = lane & 15, quad = lane >> 4;
    const int wm = w & 1, wn = w >> 1;

    const int arow = t >> 3, aseg = t & 7;   // A: float4 @ k-cols aseg*4, row arow
    const int nn = t & 31, kq = t >> 5;      // B: col nn, k rows kq*4..kq*4+3

    const float* xr0 = l0 + (r0+arow)*256 + aseg*4;
    const float* xr1 = l1 + (r0+arow)*256 + aseg*4;
    const float* wcol = (c0 < 512) ? (Wfoh + c0 + nn) : (Wfom + (c0 - 512) + nn);

    f32x4 acc = {0,0,0,0};

    float4 fa, fb;
    #define K1_LOAD(k0_) do { \
        const float* pa_ = ((k0_) < 256) ? (xr0 + (k0_)) : (xr1 + ((k0_) - 256)); \
        fa = *(const float4*)pa_; \
        const float* pb_ = wcol + ((k0_) + kq*4) * 512; \
        fb.x = pb_[0]; fb.y = pb_[512]; fb.z = pb_[1024]; fb.w = pb_[1536]; \
    } while(0)
    #define K1_STAGE(buf_) do { \
        ushort4 ah_, al_, bh_, bl_; \
        cvt4(fa, ah_, al_); cvt4(fb, bh_, bl_); \
        *(ushort4*)&Ah[buf_][arow][aseg*4] = ah_; \
        *(ushort4*)&Al[buf_][arow][aseg*4] = al_; \
        *(ushort4*)&Bh[buf_][nn][kq*4] = bh_; \
        *(ushort4*)&Bl[buf_][nn][kq*4] = bl_; \
    } while(0)

    K1_LOAD(0);
    K1_STAGE(0);
    K1_LOAD(32);
    __syncthreads();

    for (int c = 0; c < 16; ++c) {
        const int buf = c & 1;
        {
            const int ko = quad*8;
            s16x8 ah = *(const s16x8*)&Ah[buf][wm*16 + m][ko];
            s16x8 al = *(const s16x8*)&Al[buf][wm*16 + m][ko];
            s16x8 bh = *(const s16x8*)&Bh[buf][wn*16 + m][ko];
            s16x8 bl = *(const s16x8*)&Bl[buf][wn*16 + m][ko];
            acc = mfma32(ah, bh, acc);
            acc = mfma32(ah, bl, acc);
            acc = mfma32(al, bh, acc);
        }
        if (c + 1 < 16) {
            K1_STAGE(buf ^ 1);
            if (c + 2 < 16) K1_LOAD((c + 2) * 32);
            __syncthreads();
        }
    }
    #undef K1_LOAD
    #undef K1_STAGE

    {
        const int col = c0 + wn*16 + m;
        const float bias = cb[col];
        #pragma unroll
        for (int reg = 0; reg < 4; ++reg) {
            const int row = r0 + wm*16 + quad*4 + reg;
            float v = ftanh(acc[reg] + bias);
            unsigned short h = f2bf(v);
            unsigned short l = f2bf(v - bf2f(h));
            hvhi[row*1024 + col] = h;
            hvlo[row*1024 + col] = l;
        }
    }
}

// ---------- K2': P[1024][512] = exp2(LOG2E_2*(hv_half @ W2_half + bias)) ----------
// (unchanged) 32m x 32n, grid (16,32)=512 blocks, dbuf LDS.
__global__ __launch_bounds__(256) void k2_fused(
    const unsigned short* __restrict__ hvhi, const unsigned short* __restrict__ hvlo,
    const float* __restrict__ W2, const float* __restrict__ h2b,
    float* __restrict__ P)
{
    __shared__ unsigned short Ah[2][32][40], Al[2][32][40], Bh[2][32][40], Bl[2][32][40];
    const int t = threadIdx.x;
    const int r0 = blockIdx.y * 32, c0 = blockIdx.x * 32;
    const int half = (c0 >= 256) ? 1 : 0;
    const int ho = half * 512;
    const int nw = c0 & 255;
    const int w = t >> 6, lane = t & 63;
    const int m = lane & 15, quad = lane >> 4;
    const int wm = w & 1, wn = w >> 1;

    const int arow = t >> 3, aseg = t & 7;
    const int nn = t & 31, kq = t >> 5;

    const unsigned short* pAh = hvhi + (r0+arow)*1024 + ho + aseg*4;
    const unsigned short* pAl = hvlo + (r0+arow)*1024 + ho + aseg*4;
    const float* wcol = W2 + ho*256 + nw + nn;   // element k: wcol[k*256]

    f32x4 acc = {0,0,0,0};

    uint2 pa_h, pa_l;
    float4 fb;
    #define K2_LOAD(k0_) do { \
        pa_h = *(const uint2*)(pAh + (k0_)); \
        pa_l = *(const uint2*)(pAl + (k0_)); \
        const float* pb_ = wcol + ((k0_) + kq*4) * 256; \
        fb.x = pb_[0]; fb.y = pb_[256]; fb.z = pb_[512]; fb.w = pb_[768]; \
    } while(0)
    #define K2_STAGE(buf_) do { \
        ushort4 bh_, bl_; \
        cvt4(fb, bh_, bl_); \
        *(uint2*)&Ah[buf_][arow][aseg*4] = pa_h; \
        *(uint2*)&Al[buf_][arow][aseg*4] = pa_l; \
        *(ushort4*)&Bh[buf_][nn][kq*4] = bh_; \
        *(ushort4*)&Bl[buf_][nn][kq*4] = bl_; \
    } while(0)

    K2_LOAD(0);
    K2_STAGE(0);
    K2_LOAD(32);
    __syncthreads();

    for (int c = 0; c < 16; ++c) {
        const int buf = c & 1;
        {
            const int ko = quad*8;
            s16x8 ah = *(const s16x8*)&Ah[buf][wm*16 + m][ko];
            s16x8 al = *(const s16x8*)&Al[buf][wm*16 + m][ko];
            s16x8 bh = *(const s16x8*)&Bh[buf][wn*16 + m][ko];
            s16x8 bl = *(const s16x8*)&Bl[buf][wn*16 + m][ko];
            acc = mfma32(ah, bh, acc);
            acc = mfma32(ah, bl, acc);
            acc = mfma32(al, bh, acc);
        }
        if (c + 1 < 16) {
            K2_STAGE(buf ^ 1);
            if (c + 2 < 16) K2_LOAD((c + 2) * 32);
            __syncthreads();
        }
    }
    #undef K2_LOAD
    #undef K2_STAGE

    {
        const int col = c0 + wn*16 + m;
        const float bias = half ? 0.0f : h2b[col];
        #pragma unroll
        for (int reg = 0; reg < 4; ++reg) {
            const int row = r0 + wm*16 + quad*4 + reg;
            P[row*512 + col] = fexp2((acc[reg] + bias) * LOG2E_2);
        }
    }
}

// ---------- K3 v7: score[i,j] = ob + sumw - 2*sum_h w[h]/(1 + ea[i,h]*eb[j,h]) ----------
// v4 structure (32x32 tile, 2x2 outputs/thread, unroll-4 inner, runtime-indexed LDS --
// the measured-good config, VGPR~48) with ONE delta: 32-h chunks instead of 64-h.
// LDS 35.8KB -> 19.4KB/block => 8 blocks/CU (was 4). Staging = 1 float4 per array
// per thread. Inner math/rounding identical. 4-way rcp combine kept.
__global__ __launch_bounds__(256) void k3_pairwise(
    const float* __restrict__ P, const float* __restrict__ w,
    const float* __restrict__ ob, float* __restrict__ out)
{
    __shared__ float As[2][32][36];   // ea chunk: [i][hh], 144B rows (16B aligned)
    __shared__ float Bs[2][32][36];   // eb chunk: [j][hh]
    __shared__ float wls[256];
    const int tid = threadIdx.x;
    const int tx = tid & 15;          // cols tx, tx+16
    const int ty = tid >> 4;          // rows ty, ty+16
    const int i0 = blockIdx.y * 32, j0 = blockIdx.x * 32;

    wls[tid] = w[tid];

    // staging: 32 rows x 32 h per chunk = 1024 floats/array; 1 float4 per thread each
    const int ar = tid >> 3, ac = (tid & 7) * 4;

    const float* pA = P + (i0 + ar) * 512 + ac;
    const float* pB = P + (j0 + ar) * 512 + 256 + ac;

    float4 ra = *(const float4*)pA;
    float4 rb = *(const float4*)pB;

    *(float4*)&As[0][ar][ac] = ra;
    *(float4*)&Bs[0][ar][ac] = rb;
    ra = *(const float4*)(pA + 32);
    rb = *(const float4*)(pB + 32);
    __syncthreads();

    float acc[2][2] = {};

    #pragma unroll 2
    for (int c = 0; c < 8; ++c) {
        const int buf = c & 1;
        #pragma unroll 4
        for (int hh = 0; hh < 32; hh += 4) {
            float4 wv = *(const float4*)&wls[c*32 + hh];
            float4 av[2], bv[2];
            av[0] = *(const float4*)&As[buf][ty][hh];
            av[1] = *(const float4*)&As[buf][ty+16][hh];
            bv[0] = *(const float4*)&Bs[buf][tx][hh];
            bv[1] = *(const float4*)&Bs[buf][tx+16][hh];
            #pragma unroll
            for (int r = 0; r < 2; ++r)
                #pragma unroll
                for (int q = 0; q < 2; ++q) {
                    float u0 = fmaf(av[r].x, bv[q].x, 1.0f);
                    float u1 = fmaf(av[r].y, bv[q].y, 1.0f);
                    float u2 = fmaf(av[r].z, bv[q].z, 1.0f);
                    float u3 = fmaf(av[r].w, bv[q].w, 1.0f);
                    float d01 = u0 * u1;
                    float d23 = u2 * u3;
                    float p01 = fmaf(wv.x, u1, wv.y * u0);
                    float p23 = fmaf(wv.z, u3, wv.w * u2);
                    float num = fmaf(p01, d23, p23 * d01);
                    acc[r][q] = fmaf(num, frcp(d01 * d23), acc[r][q]);
                }
        }
        if (c + 1 < 8) {
            const int nb = buf ^ 1;
            *(float4*)&As[nb][ar][ac] = ra;
            *(float4*)&Bs[nb][ar][ac] = rb;
            if (c + 2 < 8) {
                const int off = (c + 2) * 32;
                ra = *(const float4*)(pA + off);
                rb = *(const float4*)(pB + off);
            }
            __syncthreads();
        }
    }

    float sumw = 0.0f;
    #pragma unroll
    for (int h = 0; h < 256; h += 4) {
        float4 wv = *(const float4*)&wls[h];
        sumw += (wv.x + wv.y) + (wv.z + wv.w);
    }
    const float base = ob[0] + sumw;
    out[(i0+ty)*1024    + j0+tx]      = base - 2.0f * acc[0][0];
    out[(i0+ty)*1024    + j0+tx+16]   = base - 2.0f * acc[0][1];
    out[(i0+ty+16)*1024 + j0+tx]      = base - 2.0f * acc[1][0];
    out[(i0+ty+16)*1024 + j0+tx+16]   = base - 2.0f * acc[1][1];
}

extern "C" void kernel_launch(void* const* d_in, const int* in_sizes, int n_in,
                              void* d_out, int out_size, void* d_ws, size_t ws_size,
                              hipStream_t stream) {
    const float* l0   = (const float*)d_in[0];  // lstms0 [1024,256]
    const float* l1   = (const float*)d_in[1];  // lstms1 [1024,256]
    const float* Wfoh = (const float*)d_in[2];  // [512,512]
    const float* Wfom = (const float*)d_in[3];  // [512,512]
    const float* cb   = (const float*)d_in[4];  // [1024]
    const float* W2   = (const float*)d_in[5];  // [1024,256]
    const float* h2b  = (const float*)d_in[6];  // [256]
    const float* w    = (const float*)d_in[7];  // [256]
    const float* ob   = (const float*)d_in[8];  // [1]
    float* out = (float*)d_out;                 // [1024,1024]

    // ws layout: hv hi/lo (4MB) + P (2MB)
    unsigned short* hv_hi = (unsigned short*)d_ws;           // [1024][1024] bf16
    unsigned short* hv_lo = hv_hi + 1024*1024;
    float*          P     = (float*)(hv_lo + 1024*1024);     // [1024][512] fp32

    k1_fused<<<dim3(32,32), 256, 0, stream>>>(l0, l1, Wfoh, Wfom, cb, hv_hi, hv_lo);
    k2_fused<<<dim3(16,32), 256, 0, stream>>>(hv_hi, hv_lo, W2, h2b, P);
    k3_pairwise<<<dim3(32,32), 256, 0, stream>>>(P, w, ob, out);
}